// Round 9
// baseline (647.904 us; speedup 1.0000x reference)
//
#include <hip/hip_runtime.h>

typedef _Float16 half_t;
typedef _Float16 half8 __attribute__((ext_vector_type(8)));
typedef float f32x4 __attribute__((ext_vector_type(4)));

// dims: T=64 B=32 V=32000 E=512 H=512 N=512 DK=256 DV=512, TB=2048

__device__ __forceinline__ void gload_lds16(const void* g, void* l) {
  __builtin_amdgcn_global_load_lds((const __attribute__((address_space(1))) void*)g,
                                   (__attribute__((address_space(3))) void*)l, 16, 0, 0);
}

// ---- kPrep: bid<4000 Wout^T->f16; 4000..4127 Wh^T->W1T/W2T; 4128 zero DEP/bars
__global__ __launch_bounds__(256) void kPrep(const float* __restrict__ Wout,
                                             half_t* __restrict__ WoutT,
                                             const float* __restrict__ Wh,
                                             half_t* __restrict__ W1T,
                                             half_t* __restrict__ W2T,
                                             int* __restrict__ DEP,
                                             int* __restrict__ bars) {
  __shared__ half_t tile[64][68];
  int bid = blockIdx.x;
  if (bid < 4000) {
    int n0 = (bid % 500) * 64, k0 = (bid / 500) * 64;
    for (int p = 0; p < 4; p++) {
      int id = p * 256 + threadIdx.x;
      int k = id >> 4, nq = id & 15;
      float4 v = *(const float4*)&Wout[(size_t)(k0 + k) * 32000 + n0 + nq * 4];
      tile[nq * 4 + 0][k] = (half_t)v.x; tile[nq * 4 + 1][k] = (half_t)v.y;
      tile[nq * 4 + 2][k] = (half_t)v.z; tile[nq * 4 + 3][k] = (half_t)v.w;
    }
    __syncthreads();
    for (int p = 0; p < 2; p++) {
      int id = p * 256 + threadIdx.x;
      int n = id >> 3, kc = id & 7;
      half8 h = *(const half8*)&tile[n][kc * 8];
      *(half8*)&WoutT[(size_t)(n0 + n) * 512 + k0 + kc * 8] = h;
    }
  } else if (bid < 4128) {
    int id2 = bid - 4000;
    int n0 = (id2 & 7) * 64, k0 = (id2 >> 3) * 64;
    for (int p = 0; p < 16; p++) {
      int id = p * 256 + threadIdx.x;
      int kk = id >> 6, nn = id & 63;
      tile[nn][kk] = (half_t)Wh[(size_t)(k0 + kk) * 512 + n0 + nn];
    }
    __syncthreads();
    half_t* out = (k0 < 512) ? W1T : W2T;
    int kb = k0 & 511;
    for (int p = 0; p < 16; p++) {
      int id = p * 256 + threadIdx.x;
      int nn = id >> 6, kk = id & 63;
      out[(size_t)(n0 + nn) * 512 + kb + kk] = tile[nn][kk];
    }
  } else {
    if (threadIdx.x < 64) DEP[threadIdx.x] = 0;
    bars[threadIdx.x] = 0;
  }
}

// ---- kEmbed: per-t fp64 mean of emb rows -> NK (fp64 + f32) --------------------
__global__ __launch_bounds__(256) void kEmbed(const int* __restrict__ tok,
                                              const float* __restrict__ emb,
                                              const float* __restrict__ Wk,
                                              double* __restrict__ NKd,
                                              float* __restrict__ NKf) {
  __shared__ double xm[512];
  int t = blockIdx.x, c = threadIdx.x;
  double s0 = 0.0, s1 = 0.0;
  for (int b = 0; b < 32; b++) {
    const float* src = emb + (size_t)tok[t * 32 + b] * 512;
    s0 += (double)src[c]; s1 += (double)src[c + 256];
  }
  xm[c] = s0 * (1.0 / 32.0);
  xm[c + 256] = s1 * (1.0 / 32.0);
  __syncthreads();
  double a = 0;
  #pragma unroll 4
  for (int i = 0; i < 512; i++) a += xm[i] * (double)Wk[(size_t)i * 256 + c];
  NKd[(size_t)t * 256 + c] = a;
  NKf[(size_t)t * 256 + c] = (float)a;
}

// ---- kQG: gather emb rows (LDS) + Xh f16 + Q fp64/fp32, 4 rows per WG ----------
__global__ __launch_bounds__(256) void kQG(const int* __restrict__ tok,
                                           const float* __restrict__ emb,
                                           const float* __restrict__ Wq,
                                           double* __restrict__ Qd,
                                           float* __restrict__ Q32,
                                           half_t* __restrict__ Xh) {
  __shared__ float xs[4][512];
  int r0 = blockIdx.x * 4;
  int tid = threadIdx.x;
  for (int rr = 0; rr < 4; rr++) {
    int row = r0 + rr;
    const float* src = emb + (size_t)tok[row] * 512;
    float v0 = src[tid], v1 = src[tid + 256];
    xs[rr][tid] = v0; xs[rr][tid + 256] = v1;
    Xh[(size_t)row * 512 + tid] = (half_t)v0;
    Xh[(size_t)row * 512 + tid + 256] = (half_t)v1;
  }
  __syncthreads();
  int d = tid;
  double a0 = 0, a1 = 0, a2 = 0, a3 = 0;
  #pragma unroll 4
  for (int i = 0; i < 512; i++) {
    double w = (double)Wq[(size_t)i * 256 + d];
    a0 += (double)xs[0][i] * w; a1 += (double)xs[1][i] * w;
    a2 += (double)xs[2][i] * w; a3 += (double)xs[3][i] * w;
  }
  Qd[(size_t)(r0 + 0) * 256 + d] = a0; Qd[(size_t)(r0 + 1) * 256 + d] = a1;
  Qd[(size_t)(r0 + 2) * 256 + d] = a2; Qd[(size_t)(r0 + 3) * 256 + d] = a3;
  Q32[(size_t)(r0 + 0) * 256 + d] = (float)a0; Q32[(size_t)(r0 + 1) * 256 + d] = (float)a1;
  Q32[(size_t)(r0 + 2) * 256 + d] = (float)a2; Q32[(size_t)(r0 + 3) * 256 + d] = (float)a3;
}

// ---- S[2048][576] = Q32 @ concat(keys0,NKf)^T (fp32 tiled GEMM) ----------------
__global__ __launch_bounds__(256) void kS(const float* __restrict__ Q32,
                                          const float* __restrict__ keys0,
                                          const float* __restrict__ NKf,
                                          float* __restrict__ S) {
  __shared__ float As[32][68];
  __shared__ float Bs[32][68];
  int m0 = blockIdx.x * 64, n0 = blockIdx.y * 64;
  int tid = threadIdx.x;
  int tx = tid & 15, ty = tid >> 4;
  float acc[4][4];
  #pragma unroll
  for (int i = 0; i < 4; i++)
    #pragma unroll
    for (int j = 0; j < 4; j++) acc[i][j] = 0.f;
  for (int kc = 0; kc < 256; kc += 32) {
    __syncthreads();
    #pragma unroll
    for (int p = 0; p < 8; p++) {
      int idx = p * 256 + tid;
      int k = idx & 31, m = idx >> 5;
      As[k][m] = Q32[(size_t)(m0 + m) * 256 + kc + k];
      int n = n0 + m;
      Bs[k][m] = (n < 512) ? keys0[(size_t)n * 256 + kc + k]
                           : NKf[(size_t)(n - 512) * 256 + kc + k];
    }
    __syncthreads();
    #pragma unroll
    for (int k = 0; k < 32; k++) {
      float4 a = *(const float4*)&As[k][ty * 4];
      float4 b = *(const float4*)&Bs[k][tx * 4];
      acc[0][0] += a.x * b.x; acc[0][1] += a.x * b.y; acc[0][2] += a.x * b.z; acc[0][3] += a.x * b.w;
      acc[1][0] += a.y * b.x; acc[1][1] += a.y * b.y; acc[1][2] += a.y * b.z; acc[1][3] += a.y * b.w;
      acc[2][0] += a.z * b.x; acc[2][1] += a.z * b.y; acc[2][2] += a.z * b.z; acc[2][3] += a.z * b.w;
      acc[3][0] += a.w * b.x; acc[3][1] += a.w * b.y; acc[3][2] += a.w * b.z; acc[3][3] += a.w * b.w;
    }
  }
  #pragma unroll
  for (int i = 0; i < 4; i++) {
    float4 o = {acc[i][0], acc[i][1], acc[i][2], acc[i][3]};
    *(float4*)&S[(size_t)(m0 + ty * 4 + i) * 576 + n0 + tx * 4] = o;
  }
}

// ---- per-row top-16 -> fp64 rescore -> top-8 + softmax + R16 + DEP -------------
__global__ __launch_bounds__(256) void kTopkRetr(const float* __restrict__ S,
                                                 const double* __restrict__ Qd,
                                                 const double* __restrict__ NKd,
                                                 const float* __restrict__ keys0,
                                                 const float* __restrict__ vals0,
                                                 float* __restrict__ WSo,
                                                 int* __restrict__ ISo,
                                                 half_t* __restrict__ R16,
                                                 int* __restrict__ DEP) {
  __shared__ float wls[4][8];
  __shared__ int ils[4][8];
  __shared__ int depf;
  int tid = threadIdx.x;
  if (tid == 0) depf = 0;
  __syncthreads();
  int r0b = blockIdx.x * 4;
  int wv = tid >> 6, lane = tid & 63;
  int row = r0b + wv;
  int t = row >> 5;
  const float* Srow = S + (size_t)row * 576;
  float v[8];
  #pragma unroll
  for (int j = 0; j < 8; j++) v[j] = Srow[j * 64 + lane];
  if (lane < t) v[0] = Srow[512 + lane];   // slot<t holds the generated key
  int ci[16];
  #pragma unroll
  for (int it = 0; it < 16; it++) {
    float bv = -1e30f; int bi = 0x7fffffff;
    #pragma unroll
    for (int j = 0; j < 8; j++) {
      int ii = j * 64 + lane;
      if (v[j] > bv || (v[j] == bv && ii < bi)) { bv = v[j]; bi = ii; }
    }
    #pragma unroll
    for (int s = 32; s > 0; s >>= 1) {
      float ov = __shfl_xor(bv, s, 64);
      int oi = __shfl_xor(bi, s, 64);
      if (ov > bv || (ov == bv && oi < bi)) { bv = ov; bi = oi; }
    }
    ci[it] = bi;
    #pragma unroll
    for (int j = 0; j < 8; j++)
      if (j * 64 + lane == bi) v[j] = -1e30f;
  }
  // fp64 rescore of the 16 candidates
  const double* qrow = Qd + (size_t)row * 256 + lane * 4;
  double q0 = qrow[0], q1 = qrow[1], q2 = qrow[2], q3 = qrow[3];
  double dv[16];
  #pragma unroll
  for (int c = 0; c < 16; c++) {
    int idx = ci[c];
    double p;
    if (idx < t) {
      const double* kr = NKd + (size_t)idx * 256 + lane * 4;
      p = q0 * kr[0] + q1 * kr[1] + q2 * kr[2] + q3 * kr[3];
    } else {
      const float* kr = keys0 + (size_t)idx * 256 + lane * 4;
      p = q0 * (double)kr[0] + q1 * (double)kr[1] + q2 * (double)kr[2] + q3 * (double)kr[3];
    }
    #pragma unroll
    for (int s = 32; s > 0; s >>= 1) p += __shfl_xor(p, s, 64);
    dv[c] = p * 0.0625;
  }
  double tv[8]; int ti[8];
  #pragma unroll
  for (int it = 0; it < 8; it++) {
    double bv = -1e300; int bi = 0x7fffffff;
    #pragma unroll
    for (int c = 0; c < 16; c++)
      if (dv[c] > bv || (dv[c] == bv && ci[c] < bi)) { bv = dv[c]; bi = ci[c]; }
    tv[it] = bv; ti[it] = bi;
    #pragma unroll
    for (int c = 0; c < 16; c++)
      if (ci[c] == bi) dv[c] = -1e300;
  }
  if (lane == 0) {
    double m = tv[0], ev[8], Z = 0;
    #pragma unroll
    for (int i2 = 0; i2 < 8; i2++) { ev[i2] = exp(tv[i2] - m); Z += ev[i2]; }
    double inv = 1.0 / Z;
    int dep = 0;
    #pragma unroll
    for (int i2 = 0; i2 < 8; i2++) {
      float w = (float)(ev[i2] * inv);
      WSo[(size_t)row * 8 + i2] = w;
      ISo[(size_t)row * 8 + i2] = ti[i2];
      wls[wv][i2] = w; ils[wv][i2] = ti[i2];
      if (ti[i2] < t) dep = 1;
    }
    if (dep) atomicOr(&depf, 1);
  }
  __syncthreads();
  if (tid == 0 && depf) atomicOr(&DEP[t], 1);
  // fast-path retrieved -> fp16
  for (int rr = 0; rr < 4; rr++) {
    float a0 = 0.f, a1 = 0.f;
    #pragma unroll
    for (int k2 = 0; k2 < 8; k2++) {
      const float* src = vals0 + (size_t)ils[rr][k2] * 512;
      a0 += wls[rr][k2] * src[tid];
      a1 += wls[rr][k2] * src[tid + 256];
    }
    R16[(size_t)(r0b + rr) * 512 + tid] = (half_t)a0;
    R16[(size_t)(r0b + rr) * 512 + tid + 256] = (half_t)a1;
  }
}

// ---- grid barrier (64 resident WGs) --------------------------------------------
__device__ __forceinline__ void gbar(int* bars, int id, int nwg) {
  __syncthreads();
  if (threadIdx.x == 0) {
    __hip_atomic_fetch_add(&bars[id], 1, __ATOMIC_ACQ_REL, __HIP_MEMORY_SCOPE_AGENT);
    while (__hip_atomic_load(&bars[id], __ATOMIC_ACQUIRE, __HIP_MEMORY_SCOPE_AGENT) < nwg)
      __builtin_amdgcn_s_sleep(4);
  }
  __syncthreads();
}

// ---- fused: concat-GEMM(T4 pipeline) + XH + HH + HM + NV + fixup ---------------
__global__ __launch_bounds__(256) void kFusedAll(
    const half_t* __restrict__ Xh, const half_t* __restrict__ R16,
    const half_t* __restrict__ W1T, const half_t* __restrict__ W2T,
    const float* __restrict__ bh, const float* __restrict__ Wv,
    const float* __restrict__ Wh, const float* __restrict__ vals0,
    const float* __restrict__ WSo, const int* __restrict__ ISo,
    const int* __restrict__ DEP, int* __restrict__ bars,
    float* __restrict__ XH, half_t* __restrict__ HH, float* __restrict__ HM,
    float* __restrict__ NV, float* __restrict__ RETR, float* __restrict__ HB) {
  __shared__ half_t lA[3][128 * 32];
  __shared__ half_t lB[3][128 * 32];
  __shared__ float hmld[512];
  __shared__ float rl[512];
  __shared__ float hm2[512];
  __shared__ int depl[64];
  int w = blockIdx.x;
  int n0 = (w & 3) * 128, m0 = (w >> 2) * 128;
  int tid = threadIdx.x, wid = tid >> 6, lane = tid & 63;
  int wm = wid >> 1, wn = wid & 1;
  f32x4 acc[4][4];
  #pragma unroll
  for (int a2 = 0; a2 < 4; a2++)
    #pragma unroll
    for (int b2 = 0; b2 < 4; b2++) acc[a2][b2] = (f32x4){0.f, 0.f, 0.f, 0.f};
  int rA = lane >> 2;
  int cswz = ((lane & 3) ^ ((lane >> 3) & 3)) * 8;
  int koffs = (((lane >> 4) ^ ((lane >> 1) & 3))) * 8;
  auto issue = [&](int j, int buf) {
    const half_t* Ap = (j < 16) ? Xh : R16;
    const half_t* Bp = (j < 16) ? W1T : W2T;
    int kk = j & 15;
    #pragma unroll
    for (int i2 = 0; i2 < 2; i2++) {
      int blk = wid * 2 + i2;
      gload_lds16(Ap + ((size_t)(m0 + blk * 16 + rA) * 512 + kk * 32 + cswz), (void*)(&lA[buf][blk * 512]));
      gload_lds16(Bp + ((size_t)(n0 + blk * 16 + rA) * 512 + kk * 32 + cswz), (void*)(&lB[buf][blk * 512]));
    }
  };
  issue(0, 0); issue(1, 1);
  for (int kt = 0; kt < 32; kt++) {
    if (kt < 31) asm volatile("s_waitcnt vmcnt(4)\n\ts_barrier" ::: "memory");
    else         asm volatile("s_waitcnt vmcnt(0)\n\ts_barrier" ::: "memory");
    int cur = kt % 3;
    half8 af[4], bf[4];
    #pragma unroll
    for (int mf = 0; mf < 4; mf++)
      af[mf] = *(const half8*)&lA[cur][(wm * 64 + mf * 16 + (lane & 15)) * 32 + koffs];
    #pragma unroll
    for (int nf = 0; nf < 4; nf++)
      bf[nf] = *(const half8*)&lB[cur][(wn * 64 + nf * 16 + (lane & 15)) * 32 + koffs];
    if (kt < 30) issue(kt + 2, (kt + 2) % 3);
    #pragma unroll
    for (int mf = 0; mf < 4; mf++)
      #pragma unroll
      for (int nf = 0; nf < 4; nf++)
        acc[mf][nf] = __builtin_amdgcn_mfma_f32_16x16x32_f16(af[mf], bf[nf], acc[mf][nf], 0, 0, 0);
    if (kt == 15) {  // acc == Xh@W1T^T : persist XH (+bias) for the fixup path
      #pragma unroll
      for (int nf = 0; nf < 4; nf++) {
        int col = n0 + wn * 64 + nf * 16 + (lane & 15);
        float bv = bh[col];
        #pragma unroll
        for (int mf = 0; mf < 4; mf++) {
          int rbase = m0 + wm * 64 + mf * 16 + (lane >> 4) * 4;
          #pragma unroll
          for (int r = 0; r < 4; r++)
            XH[(size_t)(rbase + r) * 512 + col] = acc[mf][nf][r] + bv;
        }
      }
    }
  }
  // epilogue: tanh + HH + per-t column means
  #pragma unroll
  for (int tt = 0; tt < 2; tt++) {
    #pragma unroll
    for (int nf = 0; nf < 4; nf++) {
      int col = n0 + wn * 64 + nf * 16 + (lane & 15);
      float bv = bh[col];
      float cs = 0.f;
      #pragma unroll
      for (int mfp = 0; mfp < 2; mfp++) {
        int mf = tt * 2 + mfp;
        int rbase = m0 + wm * 64 + mf * 16 + (lane >> 4) * 4;
        #pragma unroll
        for (int r = 0; r < 4; r++) {
          float v = tanhf(acc[mf][nf][r] + bv);
          HH[(size_t)(rbase + r) * 512 + col] = (half_t)v;
          cs += v;
        }
      }
      cs += __shfl_xor(cs, 16, 64);
      cs += __shfl_xor(cs, 32, 64);
      if ((lane >> 4) == 0) {
        int t = (m0 >> 5) + wm * 2 + tt;
        HM[(size_t)t * 512 + col] = cs * (1.f / 32.f);
      }
    }
  }
  gbar(bars, 0, 64);
  // NV[w] = HM[w] @ Wv
  hmld[tid] = HM[(size_t)w * 512 + tid];
  hmld[tid + 256] = HM[(size_t)w * 512 + tid + 256];
  __syncthreads();
  for (int v = tid; v < 512; v += 256) {
    float a = 0.f;
    #pragma unroll 4
    for (int i = 0; i < 512; i++) a += hmld[i] * Wv[(size_t)i * 512 + v];
    NV[(size_t)w * 512 + v] = a;
  }
  gbar(bars, 1, 64);
  if (tid < 64) depl[tid] = DEP[tid];
  __syncthreads();
  int barid = 2;
  for (int t = 0; t < 64; t++) {
    if (depl[t] == 0) continue;
    {  // phase A: retrieved with NV for idx<t
      int b = w >> 1, hf = w & 1;
      int c = hf * 256 + tid;
      int row = t * 32 + b;
      float a = 0.f;
      #pragma unroll
      for (int k2 = 0; k2 < 8; k2++) {
        int idx = ISo[(size_t)row * 8 + k2];
        float wv2 = WSo[(size_t)row * 8 + k2];
        const float* src = (idx < t) ? (NV + (size_t)idx * 512) : (vals0 + (size_t)idx * 512);
        a += wv2 * src[c];
      }
      RETR[(size_t)b * 512 + c] = a;
    }
    gbar(bars, barid++, 64);
    if (w < 32) {  // phase B: h row b
      int b = w;
      rl[tid] = RETR[(size_t)b * 512 + tid];
      rl[tid + 256] = RETR[(size_t)b * 512 + tid + 256];
      __syncthreads();
      int row = t * 32 + b;
      for (int cc = 0; cc < 2; cc++) {
        int col = cc * 256 + tid;
        float a = 0.f;
        #pragma unroll 4
        for (int i = 0; i < 512; i++) a += rl[i] * Wh[(size_t)(512 + i) * 512 + col];
        float h = tanhf(XH[(size_t)row * 512 + col] + a);
        HB[(size_t)b * 512 + col] = h;
        HH[(size_t)row * 512 + col] = (half_t)h;
      }
    }
    gbar(bars, barid++, 64);
    if (w == 0) {  // phase C: hmean + NV[t]
      for (int j = tid; j < 512; j += 256) {
        float s = 0.f;
        for (int b = 0; b < 32; b++) s += HB[(size_t)b * 512 + j];
        hm2[j] = s * (1.f / 32.f);
      }
      __syncthreads();
      for (int v = tid; v < 512; v += 256) {
        float a = 0.f;
        #pragma unroll 4
        for (int i = 0; i < 512; i++) a += hm2[i] * Wv[(size_t)i * 512 + v];
        NV[(size_t)t * 512 + v] = a;
      }
    }
    gbar(bars, barid++, 64);
  }
}

// ---- logits = HH @ WoutT^T + bout (fp16 MFMA, T4 3-buf pipeline, swizzle) ------
__global__ __launch_bounds__(256) void kLogits(const half_t* __restrict__ A,
                                               const half_t* __restrict__ Bm,
                                               const float* __restrict__ bout,
                                               float* __restrict__ C) {
  __shared__ half_t lA[3][128 * 32];
  __shared__ half_t lB[3][128 * 32];
  int lin = blockIdx.y * 250 + blockIdx.x;
  int swz = (lin & 7) * 500 + (lin >> 3);
  int m0 = (swz & 15) * 128;
  int n0 = (swz >> 4) * 128;
  int tid = threadIdx.x, wid = tid >> 6, lane = tid & 63;
  int wm = wid >> 1, wn = wid & 1;
  f32x4 acc[4][4];
  #pragma unroll
  for (int a2 = 0; a2 < 4; a2++)
    #pragma unroll
    for (int b2 = 0; b2 < 4; b2++) acc[a2][b2] = (f32x4){0.f, 0.f, 0.f, 0.f};
  int rA = lane >> 2;
  int cswz = ((lane & 3) ^ ((lane >> 3) & 3)) * 8;
  int koffs = (((lane >> 4) ^ ((lane >> 1) & 3))) * 8;
  auto issue = [&](int j, int buf) {
    #pragma unroll
    for (int i2 = 0; i2 < 2; i2++) {
      int blk = wid * 2 + i2;
      gload_lds16(A + ((size_t)(m0 + blk * 16 + rA) * 512 + j * 32 + cswz), (void*)(&lA[buf][blk * 512]));
      gload_lds16(Bm + ((size_t)(n0 + blk * 16 + rA) * 512 + j * 32 + cswz), (void*)(&lB[buf][blk * 512]));
    }
  };
  issue(0, 0); issue(1, 1);
  for (int kt = 0; kt < 16; kt++) {
    if (kt < 15) asm volatile("s_waitcnt vmcnt(4)\n\ts_barrier" ::: "memory");
    else         asm volatile("s_waitcnt vmcnt(0)\n\ts_barrier" ::: "memory");
    int cur = kt % 3;
    half8 af[4], bf[4];
    #pragma unroll
    for (int mf = 0; mf < 4; mf++)
      af[mf] = *(const half8*)&lA[cur][(wm * 64 + mf * 16 + (lane & 15)) * 32 + koffs];
    #pragma unroll
    for (int nf = 0; nf < 4; nf++)
      bf[nf] = *(const half8*)&lB[cur][(wn * 64 + nf * 16 + (lane & 15)) * 32 + koffs];
    if (kt < 14) issue(kt + 2, (kt + 2) % 3);
    #pragma unroll
    for (int mf = 0; mf < 4; mf++)
      #pragma unroll
      for (int nf = 0; nf < 4; nf++)
        acc[mf][nf] = __builtin_amdgcn_mfma_f32_16x16x32_f16(af[mf], bf[nf], acc[mf][nf], 0, 0, 0);
  }
  #pragma unroll
  for (int nf = 0; nf < 4; nf++) {
    int col = n0 + wn * 64 + nf * 16 + (lane & 15);
    float bv = bout[col];
    #pragma unroll
    for (int mf = 0; mf < 4; mf++) {
      int rbase = m0 + wm * 64 + mf * 16 + (lane >> 4) * 4;
      #pragma unroll
      for (int r = 0; r < 4; r++)
        C[(size_t)(rbase + r) * 32000 + col] = acc[mf][nf][r] + bv;
    }
  }
}

extern "C" void kernel_launch(void* const* d_in, const int* in_sizes, int n_in,
                              void* d_out, int out_size, void* d_ws, size_t ws_size,
                              hipStream_t stream) {
  (void)in_sizes; (void)n_in; (void)out_size; (void)ws_size;
  const int*   tok   = (const int*)d_in[0];
  const float* emb   = (const float*)d_in[1];
  const float* Wq    = (const float*)d_in[2];
  const float* Wk    = (const float*)d_in[3];
  const float* Wv    = (const float*)d_in[4];
  const float* Wh    = (const float*)d_in[5];
  const float* bh    = (const float*)d_in[6];
  const float* Wout  = (const float*)d_in[7];
  const float* bout  = (const float*)d_in[8];
  const float* keys0 = (const float*)d_in[9];
  const float* vals0 = (const float*)d_in[10];
  float* Cout = (float*)d_out;

  char* ws = (char*)d_ws;
  size_t off = 0;
  auto alloc = [&](size_t bytes) -> char* {
    char* p = ws + off;
    off += (bytes + 255) & ~(size_t)255;
    return p;
  };
  half_t* WoutT = (half_t*)alloc(32768000);  // [32000][512] f16
  half_t* W1T   = (half_t*)alloc(524288);    // [512][512] f16
  half_t* W2T   = (half_t*)alloc(524288);    // [512][512] f16
  half_t* Xh    = (half_t*)alloc(2097152);   // [2048][512] f16
  double* Qd    = (double*)alloc(4194304);   // [2048][256]
  float*  Q32   = (float*) alloc(2097152);   // [2048][256] f32
  double* NKd   = (double*)alloc(131072);    // [64][256]
  float*  NKf   = (float*) alloc(65536);     // [64][256] f32
  float*  Sb    = (float*) alloc(4718592);   // [2048][576] f32
  float*  XH    = (float*) alloc(4194304);   // [2048][512]
  float*  WSb   = (float*) alloc(65536);     // [2048][8]
  int*    ISb   = (int*)   alloc(65536);     // [2048][8]
  float*  NV    = (float*) alloc(131072);    // [64][512]
  half_t* R16   = (half_t*)alloc(2097152);   // [2048][512] f16
  half_t* HH    = (half_t*)alloc(2097152);   // [2048][512]
  float*  HM    = (float*) alloc(131072);    // [64][512]
  float*  RETR  = (float*) alloc(65536);     // [32][512]
  float*  HB    = (float*) alloc(65536);     // [32][512]
  int*    DEP   = (int*)   alloc(256);       // [64]
  int*    bars  = (int*)   alloc(1024);      // [256]

  // DIAGNOSIS ROUND: every non-logits kernel launched twice (all are
  // idempotent), kLogits once. dur_new = 2*(total - kLogits) + kLogits
  // => kLogits_cost = 920us - dur_new. No correctness change.
  kPrep<<<4129, 256, 0, stream>>>(Wout, WoutT, Wh, W1T, W2T, DEP, bars);
  kPrep<<<4129, 256, 0, stream>>>(Wout, WoutT, Wh, W1T, W2T, DEP, bars);
  kEmbed<<<64, 256, 0, stream>>>(tok, emb, Wk, NKd, NKf);
  kEmbed<<<64, 256, 0, stream>>>(tok, emb, Wk, NKd, NKf);
  kQG<<<512, 256, 0, stream>>>(tok, emb, Wq, Qd, Q32, Xh);
  kQG<<<512, 256, 0, stream>>>(tok, emb, Wq, Qd, Q32, Xh);
  kS<<<dim3(32, 9), 256, 0, stream>>>(Q32, keys0, NKf, Sb);
  kS<<<dim3(32, 9), 256, 0, stream>>>(Q32, keys0, NKf, Sb);
  kTopkRetr<<<512, 256, 0, stream>>>(Sb, Qd, NKd, keys0, vals0, WSb, ISb, R16, DEP);
  kTopkRetr<<<512, 256, 0, stream>>>(Sb, Qd, NKd, keys0, vals0, WSb, ISb, R16, DEP);
  kFusedAll<<<64, 256, 0, stream>>>(Xh, R16, W1T, W2T, bh, Wv, Wh, vals0,
                                    WSb, ISb, DEP, bars, XH, HH, HM, NV, RETR, HB);
  kFusedAll<<<64, 256, 0, stream>>>(Xh, R16, W1T, W2T, bh, Wv, Wh, vals0,
                                    WSb, ISb, DEP, bars, XH, HH, HM, NV, RETR, HB);
  kLogits<<<dim3(250, 16), 256, 0, stream>>>(HH, WoutT, bout, Cout);
}

// Round 10
// 327.992 us; speedup vs baseline: 1.9754x; 1.9754x over previous
//
#include <hip/hip_runtime.h>

typedef _Float16 half_t;
typedef _Float16 half8 __attribute__((ext_vector_type(8)));
typedef float f32x4 __attribute__((ext_vector_type(4)));

// dims: T=64 B=32 V=32000 E=512 H=512 N=512 DK=256 DV=512, TB=2048

__device__ __forceinline__ void gload_lds16(const void* g, void* l) {
  __builtin_amdgcn_global_load_lds((const __attribute__((address_space(1))) void*)g,
                                   (__attribute__((address_space(3))) void*)l, 16, 0, 0);
}

// ---- prepTile: pid<4000 -> Wout^T 64x64 tile; pid 4000..4127 -> Wh^T tile ------
__device__ __forceinline__ void prepTile(int pid, const float* __restrict__ Wout,
                                         half_t* __restrict__ WoutT,
                                         const float* __restrict__ Wh,
                                         half_t* __restrict__ W1T,
                                         half_t* __restrict__ W2T,
                                         char* smem) {
  half_t (*tile)[68] = (half_t(*)[68])smem;
  if (pid < 4000) {
    int n0 = (pid % 500) * 64, k0 = (pid / 500) * 64;
    for (int p = 0; p < 4; p++) {
      int id = p * 256 + threadIdx.x;
      int k = id >> 4, nq = id & 15;
      float4 v = *(const float4*)&Wout[(size_t)(k0 + k) * 32000 + n0 + nq * 4];
      tile[nq * 4 + 0][k] = (half_t)v.x; tile[nq * 4 + 1][k] = (half_t)v.y;
      tile[nq * 4 + 2][k] = (half_t)v.z; tile[nq * 4 + 3][k] = (half_t)v.w;
    }
    __syncthreads();
    for (int p = 0; p < 2; p++) {
      int id = p * 256 + threadIdx.x;
      int n = id >> 3, kc = id & 7;
      half8 h = *(const half8*)&tile[n][kc * 8];
      *(half8*)&WoutT[(size_t)(n0 + n) * 512 + k0 + kc * 8] = h;
    }
  } else {
    int id2 = pid - 4000;
    int n0 = (id2 & 7) * 64, k0 = (id2 >> 3) * 64;
    for (int p = 0; p < 16; p++) {
      int id = p * 256 + threadIdx.x;
      int kk = id >> 6, nn = id & 63;
      tile[nn][kk] = (half_t)Wh[(size_t)(k0 + kk) * 512 + n0 + nn];
    }
    __syncthreads();
    half_t* out = (k0 < 512) ? W1T : W2T;
    int kb = k0 & 511;
    for (int p = 0; p < 16; p++) {
      int id = p * 256 + threadIdx.x;
      int nn = id >> 6, kk = id & 63;
      out[(size_t)(n0 + nn) * 512 + kb + kk] = tile[nn][kk];
    }
  }
}

// ---- kGE: bid<512 kQG (gather+Xh+Q fp64/f32); bid>=512 kEmbed-split (8/t) ------
__global__ __launch_bounds__(256) void kGE(const int* __restrict__ tok,
                                           const float* __restrict__ emb,
                                           const float* __restrict__ Wq,
                                           const float* __restrict__ Wk,
                                           double* __restrict__ Qd,
                                           float* __restrict__ Q32,
                                           half_t* __restrict__ Xh,
                                           double* __restrict__ NKd,
                                           float* __restrict__ NKf) {
  __shared__ __align__(16) char smem[8192];
  int bid = blockIdx.x, tid = threadIdx.x;
  if (bid < 512) {  // kQG: 4 rows per block
    float (*xs)[512] = (float(*)[512])smem;
    int r0 = bid * 4;
    for (int rr = 0; rr < 4; rr++) {
      int row = r0 + rr;
      const float* src = emb + (size_t)tok[row] * 512;
      float v0 = src[tid], v1 = src[tid + 256];
      xs[rr][tid] = v0; xs[rr][tid + 256] = v1;
      Xh[(size_t)row * 512 + tid] = (half_t)v0;
      Xh[(size_t)row * 512 + tid + 256] = (half_t)v1;
    }
    __syncthreads();
    int d = tid;
    double a0 = 0, a1 = 0, a2 = 0, a3 = 0;
    #pragma unroll 4
    for (int i = 0; i < 512; i++) {
      double w = (double)Wq[(size_t)i * 256 + d];
      a0 += (double)xs[0][i] * w; a1 += (double)xs[1][i] * w;
      a2 += (double)xs[2][i] * w; a3 += (double)xs[3][i] * w;
    }
    Qd[(size_t)(r0 + 0) * 256 + d] = a0; Qd[(size_t)(r0 + 1) * 256 + d] = a1;
    Qd[(size_t)(r0 + 2) * 256 + d] = a2; Qd[(size_t)(r0 + 3) * 256 + d] = a3;
    Q32[(size_t)(r0 + 0) * 256 + d] = (float)a0; Q32[(size_t)(r0 + 1) * 256 + d] = (float)a1;
    Q32[(size_t)(r0 + 2) * 256 + d] = (float)a2; Q32[(size_t)(r0 + 3) * 256 + d] = (float)a3;
  } else {          // kEmbed split: 8 blocks per t, 32 NK cols each
    double* xm = (double*)smem;
    int bid2 = bid - 512, t = bid2 >> 3, ch = bid2 & 7;
    int c = tid;
    double s0 = 0.0, s1 = 0.0;
    for (int b = 0; b < 32; b++) {
      const float* src = emb + (size_t)tok[t * 32 + b] * 512;
      s0 += (double)src[c]; s1 += (double)src[c + 256];
    }
    xm[c] = s0 * (1.0 / 32.0);
    xm[c + 256] = s1 * (1.0 / 32.0);
    __syncthreads();
    if (tid < 32) {
      int d = ch * 32 + tid;
      double a = 0;
      #pragma unroll 4
      for (int i = 0; i < 512; i++) a += xm[i] * (double)Wk[(size_t)i * 256 + d];
      NKd[(size_t)t * 256 + d] = a;
      NKf[(size_t)t * 256 + d] = (float)a;
    }
  }
}

// ---- kSP: bid<288 kS; 288..2287 prep Wout tiles 0..1999; 2288 zero DEP/bars ----
__global__ __launch_bounds__(256) void kSP(const float* __restrict__ Q32,
                                           const float* __restrict__ keys0,
                                           const float* __restrict__ NKf,
                                           float* __restrict__ S,
                                           const float* __restrict__ Wout,
                                           half_t* __restrict__ WoutT,
                                           const float* __restrict__ Wh,
                                           half_t* __restrict__ W1T,
                                           half_t* __restrict__ W2T,
                                           int* __restrict__ DEP,
                                           int* __restrict__ bars) {
  __shared__ __align__(16) char smem[17408];
  int b = blockIdx.x, tid = threadIdx.x;
  if (b < 288) {  // S = Q32 @ concat(keys0,NKf)^T
    float (*As)[68] = (float(*)[68])smem;
    float (*Bs)[68] = (float(*)[68])(smem + 8704);
    int m0 = (b & 31) * 64, n0 = (b >> 5) * 64;
    int tx = tid & 15, ty = tid >> 4;
    float acc[4][4];
    #pragma unroll
    for (int i = 0; i < 4; i++)
      #pragma unroll
      for (int j = 0; j < 4; j++) acc[i][j] = 0.f;
    for (int kc = 0; kc < 256; kc += 32) {
      __syncthreads();
      #pragma unroll
      for (int p = 0; p < 8; p++) {
        int idx = p * 256 + tid;
        int k = idx & 31, m = idx >> 5;
        As[k][m] = Q32[(size_t)(m0 + m) * 256 + kc + k];
        int n = n0 + m;
        Bs[k][m] = (n < 512) ? keys0[(size_t)n * 256 + kc + k]
                             : NKf[(size_t)(n - 512) * 256 + kc + k];
      }
      __syncthreads();
      #pragma unroll
      for (int k = 0; k < 32; k++) {
        float4 a = *(const float4*)&As[k][ty * 4];
        float4 bb = *(const float4*)&Bs[k][tx * 4];
        acc[0][0] += a.x * bb.x; acc[0][1] += a.x * bb.y; acc[0][2] += a.x * bb.z; acc[0][3] += a.x * bb.w;
        acc[1][0] += a.y * bb.x; acc[1][1] += a.y * bb.y; acc[1][2] += a.y * bb.z; acc[1][3] += a.y * bb.w;
        acc[2][0] += a.z * bb.x; acc[2][1] += a.z * bb.y; acc[2][2] += a.z * bb.z; acc[2][3] += a.z * bb.w;
        acc[3][0] += a.w * bb.x; acc[3][1] += a.w * bb.y; acc[3][2] += a.w * bb.z; acc[3][3] += a.w * bb.w;
      }
    }
    #pragma unroll
    for (int i = 0; i < 4; i++) {
      float4 o = {acc[i][0], acc[i][1], acc[i][2], acc[i][3]};
      *(float4*)&S[(size_t)(m0 + ty * 4 + i) * 576 + n0 + tx * 4] = o;
    }
  } else if (b < 2288) {
    prepTile(b - 288, Wout, WoutT, Wh, W1T, W2T, smem);
  } else {
    if (tid < 64) DEP[tid] = 0;
    bars[tid] = 0;
  }
}

// ---- kTR: bid<512 topk+retr; bid>=512 prep tiles 2000..4127 --------------------
__global__ __launch_bounds__(256) void kTR(const float* __restrict__ S,
                                           const double* __restrict__ Qd,
                                           const double* __restrict__ NKd,
                                           const float* __restrict__ keys0,
                                           const float* __restrict__ vals0,
                                           float* __restrict__ WSo,
                                           int* __restrict__ ISo,
                                           half_t* __restrict__ R16,
                                           int* __restrict__ DEP,
                                           const float* __restrict__ Wout,
                                           half_t* __restrict__ WoutT,
                                           const float* __restrict__ Wh,
                                           half_t* __restrict__ W1T,
                                           half_t* __restrict__ W2T) {
  __shared__ __align__(16) char smem[8704];
  int bid = blockIdx.x, tid = threadIdx.x;
  if (bid >= 512) {
    prepTile(2000 + (bid - 512), Wout, WoutT, Wh, W1T, W2T, smem);
    return;
  }
  __shared__ float wls[4][8];
  __shared__ int ils[4][8];
  __shared__ int depf;
  if (tid == 0) depf = 0;
  __syncthreads();
  int r0b = bid * 4;
  int wv = tid >> 6, lane = tid & 63;
  int row = r0b + wv;
  int t = row >> 5;
  const float* Srow = S + (size_t)row * 576;
  float v[8];
  #pragma unroll
  for (int j = 0; j < 8; j++) v[j] = Srow[j * 64 + lane];
  if (lane < t) v[0] = Srow[512 + lane];   // slot<t holds the generated key
  int ci[12];
  #pragma unroll
  for (int it = 0; it < 12; it++) {
    float bv = -1e30f; int bi = 0x7fffffff;
    #pragma unroll
    for (int j = 0; j < 8; j++) {
      int ii = j * 64 + lane;
      if (v[j] > bv || (v[j] == bv && ii < bi)) { bv = v[j]; bi = ii; }
    }
    #pragma unroll
    for (int s = 32; s > 0; s >>= 1) {
      float ov = __shfl_xor(bv, s, 64);
      int oi = __shfl_xor(bi, s, 64);
      if (ov > bv || (ov == bv && oi < bi)) { bv = ov; bi = oi; }
    }
    ci[it] = bi;
    #pragma unroll
    for (int j = 0; j < 8; j++)
      if (j * 64 + lane == bi) v[j] = -1e30f;
  }
  // fp64 rescore of the 12 candidates
  const double* qrow = Qd + (size_t)row * 256 + lane * 4;
  double q0 = qrow[0], q1 = qrow[1], q2 = qrow[2], q3 = qrow[3];
  double dv[12];
  #pragma unroll
  for (int c = 0; c < 12; c++) {
    int idx = ci[c];
    double p;
    if (idx < t) {
      const double* kr = NKd + (size_t)idx * 256 + lane * 4;
      p = q0 * kr[0] + q1 * kr[1] + q2 * kr[2] + q3 * kr[3];
    } else {
      const float* kr = keys0 + (size_t)idx * 256 + lane * 4;
      p = q0 * (double)kr[0] + q1 * (double)kr[1] + q2 * (double)kr[2] + q3 * (double)kr[3];
    }
    #pragma unroll
    for (int s = 32; s > 0; s >>= 1) p += __shfl_xor(p, s, 64);
    dv[c] = p * 0.0625;
  }
  double tv[8]; int ti[8];
  #pragma unroll
  for (int it = 0; it < 8; it++) {
    double bv = -1e300; int bi = 0x7fffffff;
    #pragma unroll
    for (int c = 0; c < 12; c++)
      if (dv[c] > bv || (dv[c] == bv && ci[c] < bi)) { bv = dv[c]; bi = ci[c]; }
    tv[it] = bv; ti[it] = bi;
    #pragma unroll
    for (int c = 0; c < 12; c++)
      if (ci[c] == bi) dv[c] = -1e300;
  }
  if (lane == 0) {
    double m = tv[0], ev[8], Z = 0;
    #pragma unroll
    for (int i2 = 0; i2 < 8; i2++) { ev[i2] = exp(tv[i2] - m); Z += ev[i2]; }
    double inv = 1.0 / Z;
    int dep = 0;
    #pragma unroll
    for (int i2 = 0; i2 < 8; i2++) {
      float w = (float)(ev[i2] * inv);
      WSo[(size_t)row * 8 + i2] = w;
      ISo[(size_t)row * 8 + i2] = ti[i2];
      wls[wv][i2] = w; ils[wv][i2] = ti[i2];
      if (ti[i2] < t) dep = 1;
    }
    if (dep) atomicOr(&depf, 1);
  }
  __syncthreads();
  if (tid == 0 && depf) atomicOr(&DEP[t], 1);
  // fast-path retrieved -> fp16
  for (int rr = 0; rr < 4; rr++) {
    float a0 = 0.f, a1 = 0.f;
    #pragma unroll
    for (int k2 = 0; k2 < 8; k2++) {
      const float* src = vals0 + (size_t)ils[rr][k2] * 512;
      a0 += wls[rr][k2] * src[tid];
      a1 += wls[rr][k2] * src[tid + 256];
    }
    R16[(size_t)(r0b + rr) * 512 + tid] = (half_t)a0;
    R16[(size_t)(r0b + rr) * 512 + tid + 256] = (half_t)a1;
  }
}

// ---- grid barrier --------------------------------------------------------------
__device__ __forceinline__ void gbar(int* bars, int id, int nwg) {
  __syncthreads();
  if (threadIdx.x == 0) {
    __hip_atomic_fetch_add(&bars[id], 1, __ATOMIC_ACQ_REL, __HIP_MEMORY_SCOPE_AGENT);
    while (__hip_atomic_load(&bars[id], __ATOMIC_ACQUIRE, __HIP_MEMORY_SCOPE_AGENT) < nwg)
      __builtin_amdgcn_s_sleep(4);
  }
  __syncthreads();
}

// ---- kH: 256 blocks, 64x64-tile concat-GEMM + XH/HH/HM, gbar(256), NV ----------
__global__ __launch_bounds__(256) void kH(const half_t* __restrict__ Xh,
                                          const half_t* __restrict__ R16,
                                          const half_t* __restrict__ W1T,
                                          const half_t* __restrict__ W2T,
                                          const float* __restrict__ bh,
                                          const float* __restrict__ Wv,
                                          float* __restrict__ XH,
                                          half_t* __restrict__ HH,
                                          float* __restrict__ HM,
                                          float* __restrict__ NV,
                                          int* __restrict__ bars) {
  __shared__ half_t lA[3][64 * 32];
  __shared__ half_t lB[3][64 * 32];
  __shared__ float hmld[512];
  int b = blockIdx.x;
  int m0 = (b >> 3) * 64, n0 = (b & 7) * 64;
  int tid = threadIdx.x, wid = tid >> 6, lane = tid & 63;
  int wm = wid >> 1, wn = wid & 1;
  f32x4 acc[2][2];
  #pragma unroll
  for (int i = 0; i < 2; i++)
    #pragma unroll
    for (int j = 0; j < 2; j++) acc[i][j] = (f32x4){0.f, 0.f, 0.f, 0.f};
  int rA = lane >> 2;
  int cswz = ((lane & 3) ^ ((lane >> 3) & 3)) * 8;
  int koffs = (((lane >> 4) ^ ((lane >> 1) & 3))) * 8;
  auto issue = [&](int j, int buf) {
    const half_t* Ap = (j < 16) ? Xh : R16;
    const half_t* Bp = (j < 16) ? W1T : W2T;
    int kk = j & 15;
    gload_lds16(Ap + ((size_t)(m0 + wid * 16 + rA) * 512 + kk * 32 + cswz), (void*)(&lA[buf][wid * 512]));
    gload_lds16(Bp + ((size_t)(n0 + wid * 16 + rA) * 512 + kk * 32 + cswz), (void*)(&lB[buf][wid * 512]));
  };
  issue(0, 0); issue(1, 1);
  for (int kt = 0; kt < 32; kt++) {
    if (kt < 31) asm volatile("s_waitcnt vmcnt(2)\n\ts_barrier" ::: "memory");
    else         asm volatile("s_waitcnt vmcnt(0)\n\ts_barrier" ::: "memory");
    int cur = kt % 3;
    half8 af[2], bf[2];
    #pragma unroll
    for (int mf = 0; mf < 2; mf++)
      af[mf] = *(const half8*)&lA[cur][(wm * 32 + mf * 16 + (lane & 15)) * 32 + koffs];
    #pragma unroll
    for (int nf = 0; nf < 2; nf++)
      bf[nf] = *(const half8*)&lB[cur][(wn * 32 + nf * 16 + (lane & 15)) * 32 + koffs];
    if (kt < 30) issue(kt + 2, (kt + 2) % 3);
    #pragma unroll
    for (int mf = 0; mf < 2; mf++)
      #pragma unroll
      for (int nf = 0; nf < 2; nf++)
        acc[mf][nf] = __builtin_amdgcn_mfma_f32_16x16x32_f16(af[mf], bf[nf], acc[mf][nf], 0, 0, 0);
    if (kt == 15) {  // acc == Xh@W1T^T : persist XH (+bias) for the fixup path
      #pragma unroll
      for (int nf = 0; nf < 2; nf++) {
        int col = n0 + wn * 32 + nf * 16 + (lane & 15);
        float bv = bh[col];
        #pragma unroll
        for (int mf = 0; mf < 2; mf++) {
          int rbase = m0 + wm * 32 + mf * 16 + (lane >> 4) * 4;
          #pragma unroll
          for (int r = 0; r < 4; r++)
            XH[(size_t)(rbase + r) * 512 + col] = acc[mf][nf][r] + bv;
        }
      }
    }
  }
  // epilogue: tanh + HH + per-t column means (wave covers exactly one t)
  #pragma unroll
  for (int nf = 0; nf < 2; nf++) {
    int col = n0 + wn * 32 + nf * 16 + (lane & 15);
    float bv = bh[col];
    float cs = 0.f;
    #pragma unroll
    for (int mf = 0; mf < 2; mf++) {
      int rbase = m0 + wm * 32 + mf * 16 + (lane >> 4) * 4;
      #pragma unroll
      for (int r = 0; r < 4; r++) {
        float v = tanhf(acc[mf][nf][r] + bv);
        HH[(size_t)(rbase + r) * 512 + col] = (half_t)v;
        cs += v;
      }
    }
    cs += __shfl_xor(cs, 16, 64);
    cs += __shfl_xor(cs, 32, 64);
    if ((lane >> 4) == 0) {
      int t = (m0 >> 5) + wm;
      HM[(size_t)t * 512 + col] = cs * (1.f / 32.f);
    }
  }
  gbar(bars, 0, 256);
  // NV: block b -> t = b>>2, col chunk (b&3)*128
  int t2 = b >> 2, ch = b & 3;
  hmld[tid] = HM[(size_t)t2 * 512 + tid];
  hmld[tid + 256] = HM[(size_t)t2 * 512 + tid + 256];
  __syncthreads();
  if (tid < 128) {
    int col = ch * 128 + tid;
    float a = 0.f;
    #pragma unroll 4
    for (int i = 0; i < 512; i++) a += hmld[i] * Wv[(size_t)i * 512 + col];
    NV[(size_t)t2 * 512 + col] = a;
  }
}

// ---- kFixup: sequential correction for steps selecting generated slots ---------
__global__ __launch_bounds__(256) void kFixup(const int* __restrict__ DEP,
                                              int* __restrict__ bars,
                                              const float* __restrict__ XHm,
                                              const float* __restrict__ Wh,
                                              const float* __restrict__ Wv,
                                              const float* __restrict__ vals0,
                                              const float* __restrict__ WSo,
                                              const int* __restrict__ ISo,
                                              float* __restrict__ NV,
                                              float* __restrict__ RETR,
                                              float* __restrict__ HB,
                                              half_t* __restrict__ HHm) {
  __shared__ float rl[512];
  __shared__ float hm2[512];
  int w = blockIdx.x;
  int barid = 0;
  for (int t = 0; t < 64; t++) {
    if (DEP[t] == 0) continue;
    {
      int b = w >> 1, hf = w & 1;
      int c = hf * 256 + threadIdx.x;
      int row = t * 32 + b;
      float acc = 0.f;
      #pragma unroll
      for (int k2 = 0; k2 < 8; k2++) {
        int idx = ISo[(size_t)row * 8 + k2];
        float wv2 = WSo[(size_t)row * 8 + k2];
        const float* src = (idx < t) ? (NV + (size_t)idx * 512) : (vals0 + (size_t)idx * 512);
        acc += wv2 * src[c];
      }
      RETR[(size_t)b * 512 + c] = acc;
    }
    gbar(bars, barid++, 64);
    if (w < 32) {
      int b = w;
      rl[threadIdx.x] = RETR[(size_t)b * 512 + threadIdx.x];
      rl[threadIdx.x + 256] = RETR[(size_t)b * 512 + threadIdx.x + 256];
      __syncthreads();
      int row = t * 32 + b;
      for (int cc = 0; cc < 2; cc++) {
        int col = cc * 256 + threadIdx.x;
        float acc = 0.f;
        #pragma unroll 4
        for (int i = 0; i < 512; i++) acc += rl[i] * Wh[(size_t)(512 + i) * 512 + col];
        float h = tanhf(XHm[(size_t)row * 512 + col] + acc);
        HB[(size_t)b * 512 + col] = h;
        HHm[(size_t)row * 512 + col] = (half_t)h;
      }
    }
    gbar(bars, barid++, 64);
    if (w == 0) {
      for (int j = threadIdx.x; j < 512; j += 256) {
        float s = 0.f;
        for (int b = 0; b < 32; b++) s += HB[(size_t)b * 512 + j];
        hm2[j] = s * (1.f / 32.f);
      }
      __syncthreads();
      for (int v = threadIdx.x; v < 512; v += 256) {
        float a = 0.f;
        #pragma unroll 4
        for (int i = 0; i < 512; i++) a += hm2[i] * Wv[(size_t)i * 512 + v];
        NV[(size_t)t * 512 + v] = a;
      }
    }
    gbar(bars, barid++, 64);
  }
}

// ---- logits = HH @ WoutT^T + bout (fp16 MFMA, T4 3-buf pipeline, swizzle) ------
__global__ __launch_bounds__(256) void kLogits(const half_t* __restrict__ A,
                                               const half_t* __restrict__ Bm,
                                               const float* __restrict__ bout,
                                               float* __restrict__ C) {
  __shared__ half_t lA[3][128 * 32];
  __shared__ half_t lB[3][128 * 32];
  int lin = blockIdx.y * 250 + blockIdx.x;
  int swz = (lin & 7) * 500 + (lin >> 3);
  int m0 = (swz & 15) * 128;
  int n0 = (swz >> 4) * 128;
  int tid = threadIdx.x, wid = tid >> 6, lane = tid & 63;
  int wm = wid >> 1, wn = wid & 1;
  f32x4 acc[4][4];
  #pragma unroll
  for (int a2 = 0; a2 < 4; a2++)
    #pragma unroll
    for (int b2 = 0; b2 < 4; b2++) acc[a2][b2] = (f32x4){0.f, 0.f, 0.f, 0.f};
  int rA = lane >> 2;
  int cswz = ((lane & 3) ^ ((lane >> 3) & 3)) * 8;
  int koffs = (((lane >> 4) ^ ((lane >> 1) & 3))) * 8;
  auto issue = [&](int j, int buf) {
    #pragma unroll
    for (int i2 = 0; i2 < 2; i2++) {
      int blk = wid * 2 + i2;
      gload_lds16(A + ((size_t)(m0 + blk * 16 + rA) * 512 + j * 32 + cswz), (void*)(&lA[buf][blk * 512]));
      gload_lds16(Bm + ((size_t)(n0 + blk * 16 + rA) * 512 + j * 32 + cswz), (void*)(&lB[buf][blk * 512]));
    }
  };
  issue(0, 0); issue(1, 1);
  for (int kt = 0; kt < 16; kt++) {
    if (kt < 15) asm volatile("s_waitcnt vmcnt(4)\n\ts_barrier" ::: "memory");
    else         asm volatile("s_waitcnt vmcnt(0)\n\ts_barrier" ::: "memory");
    int cur = kt % 3;
    half8 af[4], bf[4];
    #pragma unroll
    for (int mf = 0; mf < 4; mf++)
      af[mf] = *(const half8*)&lA[cur][(wm * 64 + mf * 16 + (lane & 15)) * 32 + koffs];
    #pragma unroll
    for (int nf = 0; nf < 4; nf++)
      bf[nf] = *(const half8*)&lB[cur][(wn * 64 + nf * 16 + (lane & 15)) * 32 + koffs];
    if (kt < 14) issue(kt + 2, (kt + 2) % 3);
    #pragma unroll
    for (int mf = 0; mf < 4; mf++)
      #pragma unroll
      for (int nf = 0; nf < 4; nf++)
        acc[mf][nf] = __builtin_amdgcn_mfma_f32_16x16x32_f16(af[mf], bf[nf], acc[mf][nf], 0, 0, 0);
  }
  #pragma unroll
  for (int nf = 0; nf < 4; nf++) {
    int col = n0 + wn * 64 + nf * 16 + (lane & 15);
    float bv = bout[col];
    #pragma unroll
    for (int mf = 0; mf < 4; mf++) {
      int rbase = m0 + wm * 64 + mf * 16 + (lane >> 4) * 4;
      #pragma unroll
      for (int r = 0; r < 4; r++)
        C[(size_t)(rbase + r) * 32000 + col] = acc[mf][nf][r] + bv;
    }
  }
}

extern "C" void kernel_launch(void* const* d_in, const int* in_sizes, int n_in,
                              void* d_out, int out_size, void* d_ws, size_t ws_size,
                              hipStream_t stream) {
  (void)in_sizes; (void)n_in; (void)out_size; (void)ws_size;
  const int*   tok   = (const int*)d_in[0];
  const float* emb   = (const float*)d_in[1];
  const float* Wq    = (const float*)d_in[2];
  const float* Wk    = (const float*)d_in[3];
  const float* Wv    = (const float*)d_in[4];
  const float* Wh    = (const float*)d_in[5];
  const float* bh    = (const float*)d_in[6];
  const float* Wout  = (const float*)d_in[7];
  const float* bout  = (const float*)d_in[8];
  const float* keys0 = (const float*)d_in[9];
  const float* vals0 = (const float*)d_in[10];
  float* Cout = (float*)d_out;

  char* ws = (char*)d_ws;
  size_t off = 0;
  auto alloc = [&](size_t bytes) -> char* {
    char* p = ws + off;
    off += (bytes + 255) & ~(size_t)255;
    return p;
  };
  half_t* WoutT = (half_t*)alloc(32768000);  // [32000][512] f16
  half_t* W1T   = (half_t*)alloc(524288);    // [512][512] f16
  half_t* W2T   = (half_t*)alloc(524288);    // [512][512] f16
  half_t* Xh    = (half_t*)alloc(2097152);   // [2048][512] f16
  double* Qd    = (double*)alloc(4194304);   // [2048][256]
  float*  Q32   = (float*) alloc(2097152);   // [2048][256] f32
  double* NKd   = (double*)alloc(131072);    // [64][256]
  float*  NKf   = (float*) alloc(65536);     // [64][256] f32
  float*  Sb    = (float*) alloc(4718592);   // [2048][576] f32
  float*  XH    = (float*) alloc(4194304);   // [2048][512]
  float*  WSb   = (float*) alloc(65536);     // [2048][8]
  int*    ISb   = (int*)   alloc(65536);     // [2048][8]
  float*  NV    = (float*) alloc(131072);    // [64][512]
  half_t* R16   = (half_t*)alloc(2097152);   // [2048][512] f16
  half_t* HH    = (half_t*)alloc(2097152);   // [2048][512]
  float*  HM    = (float*) alloc(131072);    // [64][512]
  float*  RETR  = (float*) alloc(65536);     // [32][512]
  float*  HB    = (float*) alloc(65536);     // [32][512]
  int*    DEP   = (int*)   alloc(256);       // [64]
  int*    bars  = (int*)   alloc(1024);      // [256]

  kGE<<<1024, 256, 0, stream>>>(tok, emb, Wq, Wk, Qd, Q32, Xh, NKd, NKf);
  kSP<<<2289, 256, 0, stream>>>(Q32, keys0, NKf, Sb, Wout, WoutT, Wh, W1T, W2T, DEP, bars);
  kTR<<<2640, 256, 0, stream>>>(Sb, Qd, NKd, keys0, vals0, WSb, ISb, R16, DEP,
                                Wout, WoutT, Wh, W1T, W2T);
  kH<<<256, 256, 0, stream>>>(Xh, R16, W1T, W2T, bh, Wv, XH, HH, HM, NV, bars);
  kFixup<<<64, 256, 0, stream>>>(DEP, bars + 16, XH, Wh, Wv, vals0, WSb, ISb, NV, RETR, HB, HH);
  kLogits<<<dim3(250, 16), 256, 0, stream>>>(HH, WoutT, bout, Cout);
}